// Round 14
// baseline (530.105 us; speedup 1.0000x reference)
//
#include <hip/hip_runtime.h>
#include <hip/hip_bf16.h>

typedef unsigned short u16;
typedef unsigned int u32;
typedef __attribute__((ext_vector_type(8))) short short8;
typedef __attribute__((ext_vector_type(4))) float f32x4;
typedef __attribute__((ext_vector_type(2))) float f32x2;

#define NP 20000
#define NS 10000
#define NE 400000
#define H  512
#define FDIM 64
#define ECHUNK 16

// fused-kernel block ranges
#define NB_HIST 1563            // hist: ceil(NE/256)
#define NB_WT   2560            // wtrans: 10 mats x 16x16 tiles
#define NB_W2F  4               // w2 fragment precompute
#define NB_SC   1563            // scatter: ceil(NE/256)
#define NB_PP   2500            // proj pol: ceil(NP/8)
#define NB_PS   1250            // proj stock: ceil(NS/8)

__device__ __forceinline__ float bl16(u32 w){ return __uint_as_float(w << 16); }
__device__ __forceinline__ float bh16(u32 w){ return __uint_as_float(w & 0xffff0000u); }
__device__ __forceinline__ u16 f2bf(float f){
  u32 u = __float_as_uint(f);
  u32 r = u + 0x7fffu + ((u >> 16) & 1u);
  return (u16)(r >> 16);
}
__device__ __forceinline__ u32 pack2(float a, float b){
  return (u32)f2bf(a) | ((u32)f2bf(b) << 16);
}
// HW packed f32->bf16x2 convert (RNE), single VALU op — no builtin on gfx950 (T12/m240)
__device__ __forceinline__ u32 cvtpk_bf16(float a, float b){
  u32 d;
  asm("v_cvt_pk_bf16_f32 %0, %1, %2" : "=v"(d) : "v"(a), "v"(b));
  return d;
}
__device__ __forceinline__ void gload16(const void* g, void* l){
  __builtin_amdgcn_global_load_lds((const __attribute__((address_space(1))) u32*)g,
                                   (__attribute__((address_space(3))) u32*)l, 16, 0, 0);
}
// packed fp32 (VOP3P, gfx90a+): 2 fma / 2 add per instruction
__device__ __forceinline__ f32x2 pk_fma(f32x2 a, f32x2 b, f32x2 c){
  f32x2 d;
  asm("v_pk_fma_f32 %0, %1, %2, %3" : "=v"(d) : "v"(a), "v"(b), "v"(c));
  return d;
}
__device__ __forceinline__ f32x2 pk_add(f32x2 a, f32x2 b){
  f32x2 d;
  asm("v_pk_add_f32 %0, %1, %2" : "=v"(d) : "v"(a), "v"(b));
  return d;
}

// ---------------- fused setup: hist (ps/sp only) + wtrans + w2frag ----------------
struct TPair { const float* src; u16* dst; };
struct TArgs { TPair m[10]; };

__global__ __launch_bounds__(256) void setup_kernel(
    TArgs ta,
    const int* __restrict__ ps_dst, const int* __restrict__ sp_dst,
    int* __restrict__ cnt_s, int* __restrict__ cnt_p,
    const float* __restrict__ d2W, uint4* __restrict__ w2f)
{
  __shared__ float lds[32][33];
  int b = blockIdx.x;
  if (b < NB_HIST){
    int e = b*256 + threadIdx.x;
    if (e < NE){
      atomicAdd(&cnt_s[ps_dst[e]], 1);
      atomicAdd(&cnt_p[sp_dst[e]], 1);
    }
    return;
  }
  b -= NB_HIST;
  if (b < NB_WT){
    int mat = b >> 8;
    int rem = b & 255;
    const float* __restrict__ src = ta.m[mat].src;
    u16* __restrict__ dst = ta.m[mat].dst;
    int k0 = (rem >> 4) << 5, n0 = (rem & 15) << 5;
    int t = threadIdx.x;
    int r = t >> 3, c4 = (t & 7) << 2;
    float4 v = *(const float4*)(src + (size_t)(k0 + r)*H + n0 + c4);
    lds[r][c4+0] = v.x; lds[r][c4+1] = v.y; lds[r][c4+2] = v.z; lds[r][c4+3] = v.w;
    __syncthreads();
    uint2 o;
    o.x = pack2(lds[c4+0][r], lds[c4+1][r]);
    o.y = pack2(lds[c4+2][r], lds[c4+3][r]);
    *(uint2*)(dst + (size_t)(n0 + r)*H + k0 + c4) = o;
    return;
  }
  b -= NB_WT;
  {
    // W2 B-fragment precompute: w2f[ks*64+l] = bf16 W2[ks*32+(l>>4)*8 .. +7][l&15]
    int tid = b*256 + threadIdx.x;   // [0,1024)
    int l = tid & 63;
    int col = l & 15, g = l >> 4;
    int k = (tid >> 6)*32 + g*8;
    float v[8];
    #pragma unroll
    for (int j = 0; j < 8; ++j)
      v[j] = (col < 3) ? d2W[(size_t)(k+j)*3 + col] : 0.f;
    uint4 o;
    o.x = pack2(v[0], v[1]); o.y = pack2(v[2], v[3]);
    o.z = pack2(v[4], v[5]); o.w = pack2(v[6], v[7]);
    w2f[tid] = o;
  }
}

// ---------------- scan (wave-shuffle) ----------------
__device__ void scan_one(int* cnt, int n, int* rowptr)
{
  __shared__ int wsum[16];
  __shared__ int carry_s;
  int tid = threadIdx.x;
  int lane = tid & 63, wv = tid >> 6;
  if (tid == 0) carry_s = 0;
  for (int base = 0; base < n; base += 1024){
    __syncthreads();                       // protects carry_s/wsum reuse
    int i = base + tid;
    int v = (i < n) ? cnt[i] : 0;
    int x = v;
    #pragma unroll
    for (int off = 1; off < 64; off <<= 1){
      int t = __shfl_up(x, off);
      if (lane >= off) x += t;
    }
    if (lane == 63) wsum[wv] = x;
    __syncthreads();
    if (wv == 0 && lane < 16){
      int y = wsum[lane];
      #pragma unroll
      for (int off = 1; off < 16; off <<= 1){
        int t = __shfl_up(y, off, 16);
        if (lane >= off) y += t;
      }
      wsum[lane] = y;
    }
    __syncthreads();
    int woff = (wv > 0) ? wsum[wv-1] : 0;
    int cb = carry_s;
    int excl = cb + woff + x - v;
    if (i < n){ rowptr[i] = excl; cnt[i] = excl; }
    __syncthreads();
    if (tid == 1023) carry_s = cb + woff + x;   // running total
  }
  __syncthreads();
  if (tid == 0) rowptr[n] = carry_s;
}

__global__ __launch_bounds__(1024) void scan2_kernel(int* c0, int n0, int* r0,
                                                     int* c1, int n1, int* r1)
{
  if (blockIdx.x == 0) scan_one(c0, n0, r0);
  else scan_one(c1, n1, r1);
}

// ---------------- fused scatter (ps/sp only) + proj ----------------
__device__ void proj_body(const float* __restrict__ X, const float* __restrict__ W,
                          const float* __restrict__ b, u16* __restrict__ Y, int n,
                          int blk, float (*xs)[FDIM])
{
  int tid = threadIdx.x;
  int m0 = blk * 8;
  {
    int r = tid >> 6, c = tid & 63;
    int m = m0 + r;
    xs[r][c] = (m < n) ? X[(size_t)m*FDIM + c] : 0.f;
    m = m0 + r + 4;
    xs[r+4][c] = (m < n) ? X[(size_t)m*FDIM + c] : 0.f;
  }
  __syncthreads();
  float acc[8][2] = {};
  int c0 = tid, c1 = tid + 256;
  for (int k = 0; k < FDIM; ++k){
    float w0 = W[k*H + c0];
    float w1 = W[k*H + c1];
    #pragma unroll
    for (int r = 0; r < 8; ++r){
      float xv = xs[r][k];
      acc[r][0] = fmaf(xv, w0, acc[r][0]);
      acc[r][1] = fmaf(xv, w1, acc[r][1]);
    }
  }
  float b0 = b[c0], b1 = b[c1];
  #pragma unroll
  for (int r = 0; r < 8; ++r){
    int m = m0 + r;
    if (m < n){
      Y[(size_t)m*H + c0] = f2bf(fmaxf(acc[r][0] + b0, 0.f));
      Y[(size_t)m*H + c1] = f2bf(fmaxf(acc[r][1] + b1, 0.f));
    }
  }
}

__global__ __launch_bounds__(256) void scatter_proj_kernel(
    const int* __restrict__ ps_src, const int* __restrict__ ps_dst,
    const int* __restrict__ sp_src, const int* __restrict__ sp_dst,
    int* __restrict__ cur_s, int* __restrict__ cur_p,
    int* __restrict__ sorted_ps, int* __restrict__ sorted_sp,
    const float* __restrict__ x_pol, const float* __restrict__ Wp, const float* __restrict__ bp, u16* __restrict__ P0,
    const float* __restrict__ x_stock, const float* __restrict__ Ws_, const float* __restrict__ bs_, u16* __restrict__ S0)
{
  __shared__ float xs[8][FDIM];
  int b = blockIdx.x;
  if (b < NB_SC){
    int e = b*256 + threadIdx.x;
    if (e < NE){
      int pos = atomicAdd(&cur_s[ps_dst[e]], 1);
      sorted_ps[pos] = ps_src[e];
      int pos2 = atomicAdd(&cur_p[sp_dst[e]], 1);
      sorted_sp[pos2] = sp_src[e];
    }
    return;
  }
  b -= NB_SC;
  if (b < NB_PP){ proj_body(x_pol, Wp, bp, P0, NP, b, xs); return; }
  b -= NB_PP;
  proj_body(x_stock, Ws_, bs_, S0, NS, b, xs);
}

// ---------------- paired mean aggregation: one wave per dst row, 8 gathers in flight ----------------
__global__ __launch_bounds__(256) void agg2_kernel(
    const u16* __restrict__ X0, const int* __restrict__ rp0, const int* __restrict__ s0,
    u16* __restrict__ M0, int n0,
    const u16* __restrict__ X1, const int* __restrict__ rp1, const int* __restrict__ s1,
    u16* __restrict__ M1, int n1)
{
  int wid = (blockIdx.x << 2) + (threadIdx.x >> 6);
  int lane = threadIdx.x & 63;
  const u16* X; const int* rp; const int* ss; u16* M; int row;
  if (wid < n0){ X = X0; rp = rp0; ss = s0; M = M0; row = wid; }
  else if (wid < n0 + n1){ X = X1; rp = rp1; ss = s1; M = M1; row = wid - n0; }
  else return;
  int beg = rp[row], end = rp[row + 1];
  f32x2 ac0 = {0,0}, ac1 = {0,0}, ac2 = {0,0}, ac3 = {0,0};
  int j0 = lane << 3;
#define ACCP(v) { ac0 = pk_add(ac0, (f32x2){bl16(v.x), bh16(v.x)}); \
                  ac1 = pk_add(ac1, (f32x2){bl16(v.y), bh16(v.y)}); \
                  ac2 = pk_add(ac2, (f32x2){bl16(v.z), bh16(v.z)}); \
                  ac3 = pk_add(ac3, (f32x2){bl16(v.w), bh16(v.w)}); }
  int i = beg;
  for (; i + 8 <= end; i += 8){
    int sa = ss[i+0], sb = ss[i+1], sc = ss[i+2], sd = ss[i+3];
    int se = ss[i+4], sf = ss[i+5], sg = ss[i+6], sh = ss[i+7];
    uint4 v0 = *(const uint4*)(X + (size_t)sa*H + j0);
    uint4 v1 = *(const uint4*)(X + (size_t)sb*H + j0);
    uint4 v2 = *(const uint4*)(X + (size_t)sc*H + j0);
    uint4 v3 = *(const uint4*)(X + (size_t)sd*H + j0);
    uint4 v4 = *(const uint4*)(X + (size_t)se*H + j0);
    uint4 v5 = *(const uint4*)(X + (size_t)sf*H + j0);
    uint4 v6 = *(const uint4*)(X + (size_t)sg*H + j0);
    uint4 v7 = *(const uint4*)(X + (size_t)sh*H + j0);
    ACCP(v0); ACCP(v1); ACCP(v2); ACCP(v3);
    ACCP(v4); ACCP(v5); ACCP(v6); ACCP(v7);
  }
  for (; i + 2 <= end; i += 2){
    int sa = ss[i], sb = ss[i+1];
    uint4 v0 = *(const uint4*)(X + (size_t)sa*H + j0);
    uint4 v1 = *(const uint4*)(X + (size_t)sb*H + j0);
    ACCP(v0); ACCP(v1);
  }
  if (i < end){
    int sa = ss[i];
    uint4 v0 = *(const uint4*)(X + (size_t)sa*H + j0);
    ACCP(v0);
  }
#undef ACCP
  float inv = 1.f / (float)max(end - beg, 1);
  uint4 o;
  o.x = cvtpk_bf16(ac0.x*inv, ac0.y*inv);
  o.y = cvtpk_bf16(ac1.x*inv, ac1.y*inv);
  o.z = cvtpk_bf16(ac2.x*inv, ac2.y*inv);
  o.w = cvtpk_bf16(ac3.x*inv, ac3.y*inv);
  *(uint4*)(M + (size_t)row*H + j0) = o;
}

// ---------------- 256x256 deep-pipelined MFMA GEMM (T3+T4+T5), flattened grid ----------------
struct GemmProb {
  const u16* A1; const u16* W1t; const u16* A2; const u16* W2t;
  const float* bias; u16* C; int nrows; int relu;
};

__global__ __launch_bounds__(512) void gemm_mfma256(GemmProb Pa, GemmProb Pb, int aBlocks)
{
  int bid = blockIdx.x;
  GemmProb P; int idx;
  if (bid < aBlocks){ P = Pa; idx = bid; }
  else { P = Pb; idx = bid - aBlocks; }
  int n0 = (idx & 1) << 8;
  int m0 = (idx >> 1) << 8;
  if (m0 >= P.nrows) return;

  __shared__ u16 lds[2][2][256*64];   // [buf][A/B][rows*k] = 128 KB
  int t = threadIdx.x;
  int w = t >> 6, l = t & 63;
  int wm = w >> 2, wn = w & 3;        // 2 x 4 wave grid
  int lr = l & 15, lg = l >> 4;

  f32x4 acc[8][4];
  #pragma unroll
  for (int i = 0; i < 8; ++i)
    #pragma unroll
    for (int j = 0; j < 4; ++j)
      acc[i][j] = (f32x4){0.f, 0.f, 0.f, 0.f};

  const u16* Asrc0 = P.A1; const u16* Asrc1 = P.A2;
  const u16* Wsrc0 = P.W1t; const u16* Wsrc1 = P.W2t;
  int NT = P.A2 ? 16 : 8;

  auto STAGE = [&](int kt, int buf){
    const u16* Ap = (kt < 8) ? Asrc0 : Asrc1;
    const u16* Wp = (kt < 8) ? Wsrc0 : Wsrc1;
    int k0 = (kt & 7) << 6;
    char* AsB = (char*)lds[buf][0];
    char* BsB = (char*)lds[buf][1];
    #pragma unroll
    for (int i = 0; i < 4; ++i){
      int c = i*512 + t;
      int row = c >> 3, p = c & 7;
      int k8 = p ^ (row & 7);
      gload16(Ap + (size_t)(m0 + row)*H + k0 + k8*8, AsB + c*16);
      gload16(Wp + (size_t)(n0 + row)*H + k0 + k8*8, BsB + c*16);
    }
  };

  STAGE(0, 0);
  for (int kt = 0; kt < NT; ++kt){
    int cur = kt & 1;
    if (kt + 1 < NT){
      STAGE(kt + 1, cur ^ 1);
      asm volatile("s_waitcnt vmcnt(8)" ::: "memory");
    } else {
      asm volatile("s_waitcnt vmcnt(0)" ::: "memory");
    }
    __builtin_amdgcn_sched_barrier(0);
    __builtin_amdgcn_s_barrier();
    __builtin_amdgcn_sched_barrier(0);
    const char* AsB = (const char*)lds[cur][0];
    const char* BsB = (const char*)lds[cur][1];
    #pragma unroll
    for (int ph = 0; ph < 4; ++ph){
      const int mh = ph & 1, ks = ph >> 1;
      short8 a[4], b[4];
      int kc = (ks << 2) + lg;
      #pragma unroll
      for (int i = 0; i < 4; ++i){
        int r = (wm << 7) + (mh << 6) + (i << 4) + lr;
        a[i] = *(const short8*)(AsB + r*128 + ((kc ^ (r & 7)) << 4));
      }
      #pragma unroll
      for (int nf = 0; nf < 4; ++nf){
        int r = (wn << 6) + (nf << 4) + lr;
        b[nf] = *(const short8*)(BsB + r*128 + ((kc ^ (r & 7)) << 4));
      }
      __builtin_amdgcn_s_setprio(1);
      #pragma unroll
      for (int i = 0; i < 4; ++i)
        #pragma unroll
        for (int nf = 0; nf < 4; ++nf)
          acc[(mh << 2) + i][nf] =
            __builtin_amdgcn_mfma_f32_16x16x32_bf16(a[i], b[nf], acc[(mh << 2) + i][nf], 0, 0, 0);
      __builtin_amdgcn_s_setprio(0);
    }
    asm volatile("" ::: "memory");
    __builtin_amdgcn_s_barrier();
    __builtin_amdgcn_sched_barrier(0);
  }

  float bvn[4];
  #pragma unroll
  for (int nf = 0; nf < 4; ++nf)
    bvn[nf] = P.bias ? P.bias[n0 + (wn << 6) + (nf << 4) + lr] : 0.f;
  #pragma unroll
  for (int mf = 0; mf < 8; ++mf){
    #pragma unroll
    for (int j = 0; j < 4; ++j){
      int m = m0 + (wm << 7) + (mf << 4) + (lg << 2) + j;
      if (m < P.nrows){
        #pragma unroll
        for (int nf = 0; nf < 4; ++nf){
          float v = acc[mf][nf][j] + bvn[nf];
          if (P.relu) v = fmaxf(v, 0.f);
          P.C[(size_t)m*H + n0 + (wn << 6) + (nf << 4) + lr] = f2bf(v);
        }
      }
    }
  }
}

// ---------------- edge decoder via bf16 MFMA, CSR-free ----------------
// Grid-stride over 16-edge chunks in original edge order: sequential metadata
// reads and sequential output writes. lane l -> (edge er=l&15, group g=l>>4);
// h in f32 packed math; bf16 pack via single-op v_cvt_pk_bf16_f32 (R14) =
// the MFMA A-fragment in place; W2 B-fragments in LDS. D: row=edge, col=class.
__global__ __launch_bounds__(256) void edge_mfma_kernel(
    const u16* __restrict__ Adec, const u16* __restrict__ Bdec,   // bf16, d1b folded into Adec
    const uint4* __restrict__ w2f, const float* __restrict__ d1W,
    const float* __restrict__ d2b,
    const int* __restrict__ trow, const int* __restrict__ tcol,
    const float* __restrict__ attr,
    float* __restrict__ out)
{
  __shared__ uint4 w2s[16*64];      // 16 KB: bf16 W2 B-fragments per slice
  __shared__ float w1s[2][H];       // 4 KB: d1W rows 1024 (attr0) / 1025 (attr1)
  int t = threadIdx.x;
  #pragma unroll
  for (int i = 0; i < 4; ++i)
    w2s[i*256 + t] = w2f[i*256 + t];
  ((float4*)w1s)[t] = ((const float4*)(d1W + (size_t)1024*H))[t];   // 1024 consecutive floats
  __syncthreads();

  int lane = t & 63;
  int er = lane & 15, g = lane >> 4;
  int nch = NE / ECHUNK;
  int wstride = gridDim.x << 2;
  float ob = (er < 3) ? d2b[er] : 0.f;   // er == output class for writer lanes

  for (int ch = (blockIdx.x << 2) + (t >> 6); ch < nch; ch += wstride){
    int base = ch * ECHUNK;

    // lane i<16 loads edge base+i metadata directly (sequential, coalesced);
    // broadcasts below are in uniform control flow (R10 lesson)
    int rld = 0, cld = 0; float a0ld = 0.f, a1ld = 0.f;
    if (lane < ECHUNK){
      int e = base + lane;
      rld = trow[e]; cld = tcol[e];
      float2 av = *(const float2*)(attr + 2*(size_t)e);
      a0ld = av.x; a1ld = av.y;
    }
    int p  = __shfl(rld, er);
    int c  = __shfl(cld, er);
    float a0 = __shfl(a0ld, er);
    float a1 = __shfl(a1ld, er);
    f32x2 a0v = {a0, a0}, a1v = {a1, a1};

    const u16* Arow = Adec + (size_t)p*H + g*8;
    const u16* Brow = Bdec + (size_t)c*H + g*8;

    f32x4 acc = {0.f, 0.f, 0.f, 0.f};
    #pragma unroll
    for (int ks = 0; ks < 16; ++ks){
      uint4 va = *(const uint4*)(Arow + ks*32);
      uint4 vb = *(const uint4*)(Brow + ks*32);
      const float* wa = &w1s[0][ks*32 + g*8];
      const float* wb = &w1s[1][ks*32 + g*8];
      float4 wa0 = *(const float4*)(wa);
      float4 wa1 = *(const float4*)(wa + 4);
      float4 wb0 = *(const float4*)(wb);
      float4 wb1 = *(const float4*)(wb + 4);
      f32x2 h0 = pk_add((f32x2){bl16(va.x), bh16(va.x)}, (f32x2){bl16(vb.x), bh16(vb.x)});
      f32x2 h1 = pk_add((f32x2){bl16(va.y), bh16(va.y)}, (f32x2){bl16(vb.y), bh16(vb.y)});
      f32x2 h2 = pk_add((f32x2){bl16(va.z), bh16(va.z)}, (f32x2){bl16(vb.z), bh16(vb.z)});
      f32x2 h3 = pk_add((f32x2){bl16(va.w), bh16(va.w)}, (f32x2){bl16(vb.w), bh16(vb.w)});
      h0 = pk_fma(a0v, (f32x2){wa0.x, wa0.y}, h0);
      h1 = pk_fma(a0v, (f32x2){wa0.z, wa0.w}, h1);
      h2 = pk_fma(a0v, (f32x2){wa1.x, wa1.y}, h2);
      h3 = pk_fma(a0v, (f32x2){wa1.z, wa1.w}, h3);
      h0 = pk_fma(a1v, (f32x2){wb0.x, wb0.y}, h0);
      h1 = pk_fma(a1v, (f32x2){wb0.z, wb0.w}, h1);
      h2 = pk_fma(a1v, (f32x2){wb1.x, wb1.y}, h2);
      h3 = pk_fma(a1v, (f32x2){wb1.z, wb1.w}, h3);
      uint4 hh;
      hh.x = cvtpk_bf16(fmaxf(h0.x, 0.f), fmaxf(h0.y, 0.f));
      hh.y = cvtpk_bf16(fmaxf(h1.x, 0.f), fmaxf(h1.y, 0.f));
      hh.z = cvtpk_bf16(fmaxf(h2.x, 0.f), fmaxf(h2.y, 0.f));
      hh.w = cvtpk_bf16(fmaxf(h3.x, 0.f), fmaxf(h3.y, 0.f));
      short8 pa = __builtin_bit_cast(short8, hh);
      short8 pb = __builtin_bit_cast(short8, w2s[ks*64 + lane]);
      acc = __builtin_amdgcn_mfma_f32_16x16x32_bf16(pa, pb, acc, 0, 0, 0);
    }

    if (er < 3){
      #pragma unroll
      for (int j = 0; j < 4; ++j){
        int e = base + (g << 2) + j;           // direct, sequential output index
        out[(size_t)e*3 + er] = acc[j] + ob;
      }
    }
  }
}

extern "C" void kernel_launch(void* const* d_in, const int* in_sizes, int n_in,
                              void* d_out, int out_size, void* d_ws, size_t ws_size,
                              hipStream_t stream)
{
  const float* x_pol    = (const float*)d_in[0];
  const float* x_stock  = (const float*)d_in[1];
  const float* attr     = (const float*)d_in[2];
  const float* Wp       = (const float*)d_in[3];
  const float* bp       = (const float*)d_in[4];
  const float* Wst      = (const float*)d_in[5];
  const float* bst      = (const float*)d_in[6];
  const float* c1_ps_Wl = (const float*)d_in[7];
  const float* c1_ps_bl = (const float*)d_in[8];
  const float* c1_ps_Wr = (const float*)d_in[9];
  const float* c1_sp_Wl = (const float*)d_in[10];
  const float* c1_sp_bl = (const float*)d_in[11];
  const float* c1_sp_Wr = (const float*)d_in[12];
  const float* c2_ps_Wl = (const float*)d_in[13];
  const float* c2_ps_bl = (const float*)d_in[14];
  const float* c2_ps_Wr = (const float*)d_in[15];
  const float* c2_sp_Wl = (const float*)d_in[16];
  const float* c2_sp_bl = (const float*)d_in[17];
  const float* c2_sp_Wr = (const float*)d_in[18];
  const float* d1W      = (const float*)d_in[19];
  const float* d1b      = (const float*)d_in[20];
  const float* d2W      = (const float*)d_in[21];
  const float* d2b      = (const float*)d_in[22];
  const int* ps_src     = (const int*)d_in[23];
  const int* ps_dst     = (const int*)d_in[24];
  const int* sp_src     = (const int*)d_in[25];
  const int* sp_dst     = (const int*)d_in[26];
  const int* trow       = (const int*)d_in[27];
  const int* tcol       = (const int*)d_in[28];
  float* out = (float*)d_out;

  char* ws = (char*)d_ws;
  size_t off = 0;
  auto alloc = [&](size_t bytes)->char*{
    char* p = ws + off;
    off += (bytes + 255) & ~(size_t)255;
    return p;
  };
  u16* P0 = (u16*)alloc((size_t)NP*H*2);   // hp -> hp2
  u16* P1 = (u16*)alloc((size_t)NP*H*2);   // hp1
  u16* S0 = (u16*)alloc((size_t)NS*H*2);   // hs -> hs2
  u16* S1 = (u16*)alloc((size_t)NS*H*2);   // hs1
  u16* MP = (u16*)alloc((size_t)NP*H*2);   // mean into pol / Adec
  u16* MS = (u16*)alloc((size_t)NS*H*2);   // mean into stock / Bdec
  u16* Wt[10];
  for (int i = 0; i < 10; ++i) Wt[i] = (u16*)alloc((size_t)H*H*2);
  int* cnt_s    = (int*)alloc((size_t)NS*4);      // becomes cursor after scan
  int* cnt_p    = (int*)alloc((size_t)NP*4);
  int* rowptr_s = (int*)alloc((size_t)(NS+1)*4);
  int* rowptr_p = (int*)alloc((size_t)(NP+1)*4);
  int* sorted_ps = (int*)alloc((size_t)NE*4);
  int* sorted_sp = (int*)alloc((size_t)NE*4);
  uint4* w2f     = (uint4*)alloc((size_t)16*64*16);
  // pad region: 256-row tile-tail staging reads past last matrix stay in-bounds
  alloc((size_t)256*H*2);

  TArgs ta;
  ta.m[0] = {c1_ps_Wl, Wt[0]}; ta.m[1] = {c1_ps_Wr, Wt[1]};
  ta.m[2] = {c1_sp_Wl, Wt[2]}; ta.m[3] = {c1_sp_Wr, Wt[3]};
  ta.m[4] = {c2_ps_Wl, Wt[4]}; ta.m[5] = {c2_ps_Wr, Wt[5]};
  ta.m[6] = {c2_sp_Wl, Wt[6]}; ta.m[7] = {c2_sp_Wr, Wt[7]};
  ta.m[8] = {d1W, Wt[8]};                      // d1_W rows 0..511   (pol part)
  ta.m[9] = {d1W + (size_t)512*H, Wt[9]};      // d1_W rows 512..1023 (stock part)

  // memsets, then fused setup (hist + wtrans + w2frag)
  hipMemsetAsync(cnt_s, 0, (size_t)NS*4, stream);
  hipMemsetAsync(cnt_p, 0, (size_t)NP*4, stream);
  setup_kernel<<<NB_HIST + NB_WT + NB_W2F, 256, 0, stream>>>(
      ta, ps_dst, sp_dst, cnt_s, cnt_p, d2W, w2f);

  scan2_kernel<<<2, 1024, 0, stream>>>(cnt_s, NS, rowptr_s, cnt_p, NP, rowptr_p);

  // fused scatter (ps/sp only, latency-bound) + input projections
  scatter_proj_kernel<<<NB_SC + NB_PP + NB_PS, 256, 0, stream>>>(
      ps_src, ps_dst, sp_src, sp_dst,
      cnt_s, cnt_p, sorted_ps, sorted_sp,
      x_pol, Wp, bp, P0, x_stock, Wst, bst, S0);

  int aggGrid = (NS + NP + 3) / 4;
  int tS = ((NS + 255) / 256) * 2;   // N=512 -> 2 column tiles per M tile
  int tP = ((NP + 255) / 256) * 2;

  // conv1: MS = mean_ps(P0), MP = mean_sp(S0); then paired GEMM (flattened grid)
  agg2_kernel<<<aggGrid, 256, 0, stream>>>(P0, rowptr_s, sorted_ps, MS, NS,
                                           S0, rowptr_p, sorted_sp, MP, NP);
  {
    GemmProb a = {MS, Wt[0], S0, Wt[1], c1_ps_bl, S1, NS, 1};
    GemmProb b = {MP, Wt[2], P0, Wt[3], c1_sp_bl, P1, NP, 1};
    gemm_mfma256<<<tS + tP, 512, 0, stream>>>(a, b, tS);
  }

  // conv2
  agg2_kernel<<<aggGrid, 256, 0, stream>>>(P1, rowptr_s, sorted_ps, MS, NS,
                                           S1, rowptr_p, sorted_sp, MP, NP);
  {
    GemmProb a = {MS, Wt[4], S1, Wt[5], c2_ps_bl, S0, NS, 1};
    GemmProb b = {MP, Wt[6], P1, Wt[7], c2_sp_bl, P0, NP, 1};
    gemm_mfma256<<<tS + tP, 512, 0, stream>>>(a, b, tS);
  }

  // decoder precompute pair: Adec = hp2 @ d1W[0:512,:] + d1b (bias folded), Bdec = hs2 @ d1W[512:1024,:]
  {
    GemmProb a = {P0, Wt[8], nullptr, nullptr, d1b, MP, NP, 0};
    GemmProb b = {S0, Wt[9], nullptr, nullptr, nullptr, MS, NS, 0};
    gemm_mfma256<<<tP + tS, 512, 0, stream>>>(a, b, tP);
  }

  // edge decoder (bf16 MFMA, CSR-free): grid-stride over 16-edge chunks
  edge_mfma_kernel<<<1024, 256, 0, stream>>>(MP, MS, w2f, d1W, d2b,
                                             trow, tcol, attr, out);
}

// Round 15
// 528.714 us; speedup vs baseline: 1.0026x; 1.0026x over previous
//
#include <hip/hip_runtime.h>
#include <hip/hip_bf16.h>

typedef unsigned short u16;
typedef unsigned int u32;
typedef __attribute__((ext_vector_type(8))) short short8;
typedef __attribute__((ext_vector_type(4))) float f32x4;
typedef __attribute__((ext_vector_type(2))) float f32x2;

#define NP 20000
#define NS 10000
#define NE 400000
#define H  512
#define FDIM 64
#define ECHUNK 16

// fused-kernel block ranges
#define NB_HIST 1563            // hist: ceil(NE/256)
#define NB_WT   2560            // wtrans: 10 mats x 16x16 tiles
#define NB_W2F  4               // w2 fragment precompute
#define NB_SC   1563            // scatter: ceil(NE/256)
#define NB_PP   2500            // proj pol: ceil(NP/8)
#define NB_PS   1250            // proj stock: ceil(NS/8)

__device__ __forceinline__ float bl16(u32 w){ return __uint_as_float(w << 16); }
__device__ __forceinline__ float bh16(u32 w){ return __uint_as_float(w & 0xffff0000u); }
__device__ __forceinline__ u16 f2bf(float f){
  u32 u = __float_as_uint(f);
  u32 r = u + 0x7fffu + ((u >> 16) & 1u);
  return (u16)(r >> 16);
}
__device__ __forceinline__ u32 pack2(float a, float b){
  return (u32)f2bf(a) | ((u32)f2bf(b) << 16);
}
// HW packed f32->bf16x2 convert (RNE), single VALU op — no builtin on gfx950 (T12/m240)
__device__ __forceinline__ u32 cvtpk_bf16(float a, float b){
  u32 d;
  asm("v_cvt_pk_bf16_f32 %0, %1, %2" : "=v"(d) : "v"(a), "v"(b));
  return d;
}
__device__ __forceinline__ void gload16(const void* g, void* l){
  __builtin_amdgcn_global_load_lds((const __attribute__((address_space(1))) u32*)g,
                                   (__attribute__((address_space(3))) u32*)l, 16, 0, 0);
}
// packed fp32 (VOP3P, gfx90a+): 2 fma / 2 add per instruction
__device__ __forceinline__ f32x2 pk_fma(f32x2 a, f32x2 b, f32x2 c){
  f32x2 d;
  asm("v_pk_fma_f32 %0, %1, %2, %3" : "=v"(d) : "v"(a), "v"(b), "v"(c));
  return d;
}
__device__ __forceinline__ f32x2 pk_add(f32x2 a, f32x2 b){
  f32x2 d;
  asm("v_pk_add_f32 %0, %1, %2" : "=v"(d) : "v"(a), "v"(b));
  return d;
}

// ---------------- fused setup: hist (ps/sp only) + wtrans + w2frag ----------------
struct TPair { const float* src; u16* dst; };
struct TArgs { TPair m[10]; };

__global__ __launch_bounds__(256) void setup_kernel(
    TArgs ta,
    const int* __restrict__ ps_dst, const int* __restrict__ sp_dst,
    int* __restrict__ cnt_s, int* __restrict__ cnt_p,
    const float* __restrict__ d2W, uint4* __restrict__ w2f)
{
  __shared__ float lds[32][33];
  int b = blockIdx.x;
  if (b < NB_HIST){
    int e = b*256 + threadIdx.x;
    if (e < NE){
      atomicAdd(&cnt_s[ps_dst[e]], 1);
      atomicAdd(&cnt_p[sp_dst[e]], 1);
    }
    return;
  }
  b -= NB_HIST;
  if (b < NB_WT){
    int mat = b >> 8;
    int rem = b & 255;
    const float* __restrict__ src = ta.m[mat].src;
    u16* __restrict__ dst = ta.m[mat].dst;
    int k0 = (rem >> 4) << 5, n0 = (rem & 15) << 5;
    int t = threadIdx.x;
    int r = t >> 3, c4 = (t & 7) << 2;
    float4 v = *(const float4*)(src + (size_t)(k0 + r)*H + n0 + c4);
    lds[r][c4+0] = v.x; lds[r][c4+1] = v.y; lds[r][c4+2] = v.z; lds[r][c4+3] = v.w;
    __syncthreads();
    uint2 o;
    o.x = pack2(lds[c4+0][r], lds[c4+1][r]);
    o.y = pack2(lds[c4+2][r], lds[c4+3][r]);
    *(uint2*)(dst + (size_t)(n0 + r)*H + k0 + c4) = o;
    return;
  }
  b -= NB_WT;
  {
    // W2 B-fragment precompute: w2f[ks*64+l] = bf16 W2[ks*32+(l>>4)*8 .. +7][l&15]
    int tid = b*256 + threadIdx.x;   // [0,1024)
    int l = tid & 63;
    int col = l & 15, g = l >> 4;
    int k = (tid >> 6)*32 + g*8;
    float v[8];
    #pragma unroll
    for (int j = 0; j < 8; ++j)
      v[j] = (col < 3) ? d2W[(size_t)(k+j)*3 + col] : 0.f;
    uint4 o;
    o.x = pack2(v[0], v[1]); o.y = pack2(v[2], v[3]);
    o.z = pack2(v[4], v[5]); o.w = pack2(v[6], v[7]);
    w2f[tid] = o;
  }
}

// ---------------- scan (wave-shuffle) ----------------
__device__ void scan_one(int* cnt, int n, int* rowptr)
{
  __shared__ int wsum[16];
  __shared__ int carry_s;
  int tid = threadIdx.x;
  int lane = tid & 63, wv = tid >> 6;
  if (tid == 0) carry_s = 0;
  for (int base = 0; base < n; base += 1024){
    __syncthreads();                       // protects carry_s/wsum reuse
    int i = base + tid;
    int v = (i < n) ? cnt[i] : 0;
    int x = v;
    #pragma unroll
    for (int off = 1; off < 64; off <<= 1){
      int t = __shfl_up(x, off);
      if (lane >= off) x += t;
    }
    if (lane == 63) wsum[wv] = x;
    __syncthreads();
    if (wv == 0 && lane < 16){
      int y = wsum[lane];
      #pragma unroll
      for (int off = 1; off < 16; off <<= 1){
        int t = __shfl_up(y, off, 16);
        if (lane >= off) y += t;
      }
      wsum[lane] = y;
    }
    __syncthreads();
    int woff = (wv > 0) ? wsum[wv-1] : 0;
    int cb = carry_s;
    int excl = cb + woff + x - v;
    if (i < n){ rowptr[i] = excl; cnt[i] = excl; }
    __syncthreads();
    if (tid == 1023) carry_s = cb + woff + x;   // running total
  }
  __syncthreads();
  if (tid == 0) rowptr[n] = carry_s;
}

__global__ __launch_bounds__(1024) void scan2_kernel(int* c0, int n0, int* r0,
                                                     int* c1, int n1, int* r1)
{
  if (blockIdx.x == 0) scan_one(c0, n0, r0);
  else scan_one(c1, n1, r1);
}

// ---------------- fused scatter (ps/sp only) + proj ----------------
__device__ void proj_body(const float* __restrict__ X, const float* __restrict__ W,
                          const float* __restrict__ b, u16* __restrict__ Y, int n,
                          int blk, float (*xs)[FDIM])
{
  int tid = threadIdx.x;
  int m0 = blk * 8;
  {
    int r = tid >> 6, c = tid & 63;
    int m = m0 + r;
    xs[r][c] = (m < n) ? X[(size_t)m*FDIM + c] : 0.f;
    m = m0 + r + 4;
    xs[r+4][c] = (m < n) ? X[(size_t)m*FDIM + c] : 0.f;
  }
  __syncthreads();
  float acc[8][2] = {};
  int c0 = tid, c1 = tid + 256;
  for (int k = 0; k < FDIM; ++k){
    float w0 = W[k*H + c0];
    float w1 = W[k*H + c1];
    #pragma unroll
    for (int r = 0; r < 8; ++r){
      float xv = xs[r][k];
      acc[r][0] = fmaf(xv, w0, acc[r][0]);
      acc[r][1] = fmaf(xv, w1, acc[r][1]);
    }
  }
  float b0 = b[c0], b1 = b[c1];
  #pragma unroll
  for (int r = 0; r < 8; ++r){
    int m = m0 + r;
    if (m < n){
      Y[(size_t)m*H + c0] = f2bf(fmaxf(acc[r][0] + b0, 0.f));
      Y[(size_t)m*H + c1] = f2bf(fmaxf(acc[r][1] + b1, 0.f));
    }
  }
}

__global__ __launch_bounds__(256) void scatter_proj_kernel(
    const int* __restrict__ ps_src, const int* __restrict__ ps_dst,
    const int* __restrict__ sp_src, const int* __restrict__ sp_dst,
    int* __restrict__ cur_s, int* __restrict__ cur_p,
    int* __restrict__ sorted_ps, int* __restrict__ sorted_sp,
    const float* __restrict__ x_pol, const float* __restrict__ Wp, const float* __restrict__ bp, u16* __restrict__ P0,
    const float* __restrict__ x_stock, const float* __restrict__ Ws_, const float* __restrict__ bs_, u16* __restrict__ S0)
{
  __shared__ float xs[8][FDIM];
  int b = blockIdx.x;
  if (b < NB_SC){
    int e = b*256 + threadIdx.x;
    if (e < NE){
      int pos = atomicAdd(&cur_s[ps_dst[e]], 1);
      sorted_ps[pos] = ps_src[e];
      int pos2 = atomicAdd(&cur_p[sp_dst[e]], 1);
      sorted_sp[pos2] = sp_src[e];
    }
    return;
  }
  b -= NB_SC;
  if (b < NB_PP){ proj_body(x_pol, Wp, bp, P0, NP, b, xs); return; }
  b -= NB_PP;
  proj_body(x_stock, Ws_, bs_, S0, NS, b, xs);
}

// ---------------- paired mean aggregation: one wave per dst row, 8 gathers in flight ----------------
__global__ __launch_bounds__(256) void agg2_kernel(
    const u16* __restrict__ X0, const int* __restrict__ rp0, const int* __restrict__ s0,
    u16* __restrict__ M0, int n0,
    const u16* __restrict__ X1, const int* __restrict__ rp1, const int* __restrict__ s1,
    u16* __restrict__ M1, int n1)
{
  int wid = (blockIdx.x << 2) + (threadIdx.x >> 6);
  int lane = threadIdx.x & 63;
  const u16* X; const int* rp; const int* ss; u16* M; int row;
  if (wid < n0){ X = X0; rp = rp0; ss = s0; M = M0; row = wid; }
  else if (wid < n0 + n1){ X = X1; rp = rp1; ss = s1; M = M1; row = wid - n0; }
  else return;
  int beg = rp[row], end = rp[row + 1];
  f32x2 ac0 = {0,0}, ac1 = {0,0}, ac2 = {0,0}, ac3 = {0,0};
  int j0 = lane << 3;
#define ACCP(v) { ac0 = pk_add(ac0, (f32x2){bl16(v.x), bh16(v.x)}); \
                  ac1 = pk_add(ac1, (f32x2){bl16(v.y), bh16(v.y)}); \
                  ac2 = pk_add(ac2, (f32x2){bl16(v.z), bh16(v.z)}); \
                  ac3 = pk_add(ac3, (f32x2){bl16(v.w), bh16(v.w)}); }
  int i = beg;
  for (; i + 8 <= end; i += 8){
    int sa = ss[i+0], sb = ss[i+1], sc = ss[i+2], sd = ss[i+3];
    int se = ss[i+4], sf = ss[i+5], sg = ss[i+6], sh = ss[i+7];
    uint4 v0 = *(const uint4*)(X + (size_t)sa*H + j0);
    uint4 v1 = *(const uint4*)(X + (size_t)sb*H + j0);
    uint4 v2 = *(const uint4*)(X + (size_t)sc*H + j0);
    uint4 v3 = *(const uint4*)(X + (size_t)sd*H + j0);
    uint4 v4 = *(const uint4*)(X + (size_t)se*H + j0);
    uint4 v5 = *(const uint4*)(X + (size_t)sf*H + j0);
    uint4 v6 = *(const uint4*)(X + (size_t)sg*H + j0);
    uint4 v7 = *(const uint4*)(X + (size_t)sh*H + j0);
    ACCP(v0); ACCP(v1); ACCP(v2); ACCP(v3);
    ACCP(v4); ACCP(v5); ACCP(v6); ACCP(v7);
  }
  for (; i + 2 <= end; i += 2){
    int sa = ss[i], sb = ss[i+1];
    uint4 v0 = *(const uint4*)(X + (size_t)sa*H + j0);
    uint4 v1 = *(const uint4*)(X + (size_t)sb*H + j0);
    ACCP(v0); ACCP(v1);
  }
  if (i < end){
    int sa = ss[i];
    uint4 v0 = *(const uint4*)(X + (size_t)sa*H + j0);
    ACCP(v0);
  }
#undef ACCP
  float inv = 1.f / (float)max(end - beg, 1);
  uint4 o;
  o.x = cvtpk_bf16(ac0.x*inv, ac0.y*inv);
  o.y = cvtpk_bf16(ac1.x*inv, ac1.y*inv);
  o.z = cvtpk_bf16(ac2.x*inv, ac2.y*inv);
  o.w = cvtpk_bf16(ac3.x*inv, ac3.y*inv);
  *(uint4*)(M + (size_t)row*H + j0) = o;
}

// ---------------- 256x256 deep-pipelined MFMA GEMM (T3+T4+T5), flattened grid ----------------
struct GemmProb {
  const u16* A1; const u16* W1t; const u16* A2; const u16* W2t;
  const float* bias; u16* C; int nrows; int relu;
};

__global__ __launch_bounds__(512) void gemm_mfma256(GemmProb Pa, GemmProb Pb, int aBlocks)
{
  int bid = blockIdx.x;
  GemmProb P; int idx;
  if (bid < aBlocks){ P = Pa; idx = bid; }
  else { P = Pb; idx = bid - aBlocks; }
  int n0 = (idx & 1) << 8;
  int m0 = (idx >> 1) << 8;
  if (m0 >= P.nrows) return;

  __shared__ u16 lds[2][2][256*64];   // [buf][A/B][rows*k] = 128 KB
  int t = threadIdx.x;
  int w = t >> 6, l = t & 63;
  int wm = w >> 2, wn = w & 3;        // 2 x 4 wave grid
  int lr = l & 15, lg = l >> 4;

  f32x4 acc[8][4];
  #pragma unroll
  for (int i = 0; i < 8; ++i)
    #pragma unroll
    for (int j = 0; j < 4; ++j)
      acc[i][j] = (f32x4){0.f, 0.f, 0.f, 0.f};

  const u16* Asrc0 = P.A1; const u16* Asrc1 = P.A2;
  const u16* Wsrc0 = P.W1t; const u16* Wsrc1 = P.W2t;
  int NT = P.A2 ? 16 : 8;

  auto STAGE = [&](int kt, int buf){
    const u16* Ap = (kt < 8) ? Asrc0 : Asrc1;
    const u16* Wp = (kt < 8) ? Wsrc0 : Wsrc1;
    int k0 = (kt & 7) << 6;
    char* AsB = (char*)lds[buf][0];
    char* BsB = (char*)lds[buf][1];
    #pragma unroll
    for (int i = 0; i < 4; ++i){
      int c = i*512 + t;
      int row = c >> 3, p = c & 7;
      int k8 = p ^ (row & 7);
      gload16(Ap + (size_t)(m0 + row)*H + k0 + k8*8, AsB + c*16);
      gload16(Wp + (size_t)(n0 + row)*H + k0 + k8*8, BsB + c*16);
    }
  };

  STAGE(0, 0);
  for (int kt = 0; kt < NT; ++kt){
    int cur = kt & 1;
    if (kt + 1 < NT){
      STAGE(kt + 1, cur ^ 1);
      asm volatile("s_waitcnt vmcnt(8)" ::: "memory");
    } else {
      asm volatile("s_waitcnt vmcnt(0)" ::: "memory");
    }
    __builtin_amdgcn_sched_barrier(0);
    __builtin_amdgcn_s_barrier();
    __builtin_amdgcn_sched_barrier(0);
    const char* AsB = (const char*)lds[cur][0];
    const char* BsB = (const char*)lds[cur][1];
    #pragma unroll
    for (int ph = 0; ph < 4; ++ph){
      const int mh = ph & 1, ks = ph >> 1;
      short8 a[4], b[4];
      int kc = (ks << 2) + lg;
      #pragma unroll
      for (int i = 0; i < 4; ++i){
        int r = (wm << 7) + (mh << 6) + (i << 4) + lr;
        a[i] = *(const short8*)(AsB + r*128 + ((kc ^ (r & 7)) << 4));
      }
      #pragma unroll
      for (int nf = 0; nf < 4; ++nf){
        int r = (wn << 6) + (nf << 4) + lr;
        b[nf] = *(const short8*)(BsB + r*128 + ((kc ^ (r & 7)) << 4));
      }
      __builtin_amdgcn_s_setprio(1);
      #pragma unroll
      for (int i = 0; i < 4; ++i)
        #pragma unroll
        for (int nf = 0; nf < 4; ++nf)
          acc[(mh << 2) + i][nf] =
            __builtin_amdgcn_mfma_f32_16x16x32_bf16(a[i], b[nf], acc[(mh << 2) + i][nf], 0, 0, 0);
      __builtin_amdgcn_s_setprio(0);
    }
    asm volatile("" ::: "memory");
    __builtin_amdgcn_s_barrier();
    __builtin_amdgcn_sched_barrier(0);
  }

  float bvn[4];
  #pragma unroll
  for (int nf = 0; nf < 4; ++nf)
    bvn[nf] = P.bias ? P.bias[n0 + (wn << 6) + (nf << 4) + lr] : 0.f;
  #pragma unroll
  for (int mf = 0; mf < 8; ++mf){
    #pragma unroll
    for (int j = 0; j < 4; ++j){
      int m = m0 + (wm << 7) + (mf << 4) + (lg << 2) + j;
      if (m < P.nrows){
        #pragma unroll
        for (int nf = 0; nf < 4; ++nf){
          float v = acc[mf][nf][j] + bvn[nf];
          if (P.relu) v = fmaxf(v, 0.f);
          P.C[(size_t)m*H + n0 + (wn << 6) + (nf << 4) + lr] = f2bf(v);
        }
      }
    }
  }
}

// ---------------- edge decoder via bf16 MFMA, CSR-free ----------------
// Grid-stride over 16-edge chunks in original edge order: sequential metadata
// reads and sequential output writes. lane l -> (edge er=l&15, group g=l>>4);
// h in f32 packed math; bf16 pack via single-op v_cvt_pk_bf16_f32 = the MFMA
// A-fragment in place; W2 B-fragments in LDS. D: row=edge, col=class.
// R15: grid 2048 (20KB LDS -> 8 blocks/CU, 32 waves/CU) — kernel is
// gather-LATENCY bound (R14: same dur at 5MB hbm traffic), occupancy is the lever.
__global__ __launch_bounds__(256) void edge_mfma_kernel(
    const u16* __restrict__ Adec, const u16* __restrict__ Bdec,   // bf16, d1b folded into Adec
    const uint4* __restrict__ w2f, const float* __restrict__ d1W,
    const float* __restrict__ d2b,
    const int* __restrict__ trow, const int* __restrict__ tcol,
    const float* __restrict__ attr,
    float* __restrict__ out)
{
  __shared__ uint4 w2s[16*64];      // 16 KB: bf16 W2 B-fragments per slice
  __shared__ float w1s[2][H];       // 4 KB: d1W rows 1024 (attr0) / 1025 (attr1)
  int t = threadIdx.x;
  #pragma unroll
  for (int i = 0; i < 4; ++i)
    w2s[i*256 + t] = w2f[i*256 + t];
  ((float4*)w1s)[t] = ((const float4*)(d1W + (size_t)1024*H))[t];   // 1024 consecutive floats
  __syncthreads();

  int lane = t & 63;
  int er = lane & 15, g = lane >> 4;
  int nch = NE / ECHUNK;
  int wstride = gridDim.x << 2;
  float ob = (er < 3) ? d2b[er] : 0.f;   // er == output class for writer lanes

  for (int ch = (blockIdx.x << 2) + (t >> 6); ch < nch; ch += wstride){
    int base = ch * ECHUNK;

    // lane i<16 loads edge base+i metadata directly (sequential, coalesced);
    // broadcasts below are in uniform control flow (R10 lesson)
    int rld = 0, cld = 0; float a0ld = 0.f, a1ld = 0.f;
    if (lane < ECHUNK){
      int e = base + lane;
      rld = trow[e]; cld = tcol[e];
      float2 av = *(const float2*)(attr + 2*(size_t)e);
      a0ld = av.x; a1ld = av.y;
    }
    int p  = __shfl(rld, er);
    int c  = __shfl(cld, er);
    float a0 = __shfl(a0ld, er);
    float a1 = __shfl(a1ld, er);
    f32x2 a0v = {a0, a0}, a1v = {a1, a1};

    const u16* Arow = Adec + (size_t)p*H + g*8;
    const u16* Brow = Bdec + (size_t)c*H + g*8;

    f32x4 acc = {0.f, 0.f, 0.f, 0.f};
    #pragma unroll
    for (int ks = 0; ks < 16; ++ks){
      uint4 va = *(const uint4*)(Arow + ks*32);
      uint4 vb = *(const uint4*)(Brow + ks*32);
      const float* wa = &w1s[0][ks*32 + g*8];
      const float* wb = &w1s[1][ks*32 + g*8];
      float4 wa0 = *(const float4*)(wa);
      float4 wa1 = *(const float4*)(wa + 4);
      float4 wb0 = *(const float4*)(wb);
      float4 wb1 = *(const float4*)(wb + 4);
      f32x2 h0 = pk_add((f32x2){bl16(va.x), bh16(va.x)}, (f32x2){bl16(vb.x), bh16(vb.x)});
      f32x2 h1 = pk_add((f32x2){bl16(va.y), bh16(va.y)}, (f32x2){bl16(vb.y), bh16(vb.y)});
      f32x2 h2 = pk_add((f32x2){bl16(va.z), bh16(va.z)}, (f32x2){bl16(vb.z), bh16(vb.z)});
      f32x2 h3 = pk_add((f32x2){bl16(va.w), bh16(va.w)}, (f32x2){bl16(vb.w), bh16(vb.w)});
      h0 = pk_fma(a0v, (f32x2){wa0.x, wa0.y}, h0);
      h1 = pk_fma(a0v, (f32x2){wa0.z, wa0.w}, h1);
      h2 = pk_fma(a0v, (f32x2){wa1.x, wa1.y}, h2);
      h3 = pk_fma(a0v, (f32x2){wa1.z, wa1.w}, h3);
      h0 = pk_fma(a1v, (f32x2){wb0.x, wb0.y}, h0);
      h1 = pk_fma(a1v, (f32x2){wb0.z, wb0.w}, h1);
      h2 = pk_fma(a1v, (f32x2){wb1.x, wb1.y}, h2);
      h3 = pk_fma(a1v, (f32x2){wb1.z, wb1.w}, h3);
      uint4 hh;
      hh.x = cvtpk_bf16(fmaxf(h0.x, 0.f), fmaxf(h0.y, 0.f));
      hh.y = cvtpk_bf16(fmaxf(h1.x, 0.f), fmaxf(h1.y, 0.f));
      hh.z = cvtpk_bf16(fmaxf(h2.x, 0.f), fmaxf(h2.y, 0.f));
      hh.w = cvtpk_bf16(fmaxf(h3.x, 0.f), fmaxf(h3.y, 0.f));
      short8 pa = __builtin_bit_cast(short8, hh);
      short8 pb = __builtin_bit_cast(short8, w2s[ks*64 + lane]);
      acc = __builtin_amdgcn_mfma_f32_16x16x32_bf16(pa, pb, acc, 0, 0, 0);
    }

    if (er < 3){
      #pragma unroll
      for (int j = 0; j < 4; ++j){
        int e = base + (g << 2) + j;           // direct, sequential output index
        out[(size_t)e*3 + er] = acc[j] + ob;
      }
    }
  }
}

extern "C" void kernel_launch(void* const* d_in, const int* in_sizes, int n_in,
                              void* d_out, int out_size, void* d_ws, size_t ws_size,
                              hipStream_t stream)
{
  const float* x_pol    = (const float*)d_in[0];
  const float* x_stock  = (const float*)d_in[1];
  const float* attr     = (const float*)d_in[2];
  const float* Wp       = (const float*)d_in[3];
  const float* bp       = (const float*)d_in[4];
  const float* Wst      = (const float*)d_in[5];
  const float* bst      = (const float*)d_in[6];
  const float* c1_ps_Wl = (const float*)d_in[7];
  const float* c1_ps_bl = (const float*)d_in[8];
  const float* c1_ps_Wr = (const float*)d_in[9];
  const float* c1_sp_Wl = (const float*)d_in[10];
  const float* c1_sp_bl = (const float*)d_in[11];
  const float* c1_sp_Wr = (const float*)d_in[12];
  const float* c2_ps_Wl = (const float*)d_in[13];
  const float* c2_ps_bl = (const float*)d_in[14];
  const float* c2_ps_Wr = (const float*)d_in[15];
  const float* c2_sp_Wl = (const float*)d_in[16];
  const float* c2_sp_bl = (const float*)d_in[17];
  const float* c2_sp_Wr = (const float*)d_in[18];
  const float* d1W      = (const float*)d_in[19];
  const float* d1b      = (const float*)d_in[20];
  const float* d2W      = (const float*)d_in[21];
  const float* d2b      = (const float*)d_in[22];
  const int* ps_src     = (const int*)d_in[23];
  const int* ps_dst     = (const int*)d_in[24];
  const int* sp_src     = (const int*)d_in[25];
  const int* sp_dst     = (const int*)d_in[26];
  const int* trow       = (const int*)d_in[27];
  const int* tcol       = (const int*)d_in[28];
  float* out = (float*)d_out;

  char* ws = (char*)d_ws;
  size_t off = 0;
  auto alloc = [&](size_t bytes)->char*{
    char* p = ws + off;
    off += (bytes + 255) & ~(size_t)255;
    return p;
  };
  u16* P0 = (u16*)alloc((size_t)NP*H*2);   // hp -> hp2
  u16* P1 = (u16*)alloc((size_t)NP*H*2);   // hp1
  u16* S0 = (u16*)alloc((size_t)NS*H*2);   // hs -> hs2
  u16* S1 = (u16*)alloc((size_t)NS*H*2);   // hs1
  u16* MP = (u16*)alloc((size_t)NP*H*2);   // mean into pol / Adec
  u16* MS = (u16*)alloc((size_t)NS*H*2);   // mean into stock / Bdec
  u16* Wt[10];
  for (int i = 0; i < 10; ++i) Wt[i] = (u16*)alloc((size_t)H*H*2);
  int* cnt_s    = (int*)alloc((size_t)NS*4);      // becomes cursor after scan
  int* cnt_p    = (int*)alloc((size_t)NP*4);
  int* rowptr_s = (int*)alloc((size_t)(NS+1)*4);
  int* rowptr_p = (int*)alloc((size_t)(NP+1)*4);
  int* sorted_ps = (int*)alloc((size_t)NE*4);
  int* sorted_sp = (int*)alloc((size_t)NE*4);
  uint4* w2f     = (uint4*)alloc((size_t)16*64*16);
  // pad region: 256-row tile-tail staging reads past last matrix stay in-bounds
  alloc((size_t)256*H*2);

  TArgs ta;
  ta.m[0] = {c1_ps_Wl, Wt[0]}; ta.m[1] = {c1_ps_Wr, Wt[1]};
  ta.m[2] = {c1_sp_Wl, Wt[2]}; ta.m[3] = {c1_sp_Wr, Wt[3]};
  ta.m[4] = {c2_ps_Wl, Wt[4]}; ta.m[5] = {c2_ps_Wr, Wt[5]};
  ta.m[6] = {c2_sp_Wl, Wt[6]}; ta.m[7] = {c2_sp_Wr, Wt[7]};
  ta.m[8] = {d1W, Wt[8]};                      // d1_W rows 0..511   (pol part)
  ta.m[9] = {d1W + (size_t)512*H, Wt[9]};      // d1_W rows 512..1023 (stock part)

  // memsets, then fused setup (hist + wtrans + w2frag)
  hipMemsetAsync(cnt_s, 0, (size_t)NS*4, stream);
  hipMemsetAsync(cnt_p, 0, (size_t)NP*4, stream);
  setup_kernel<<<NB_HIST + NB_WT + NB_W2F, 256, 0, stream>>>(
      ta, ps_dst, sp_dst, cnt_s, cnt_p, d2W, w2f);

  scan2_kernel<<<2, 1024, 0, stream>>>(cnt_s, NS, rowptr_s, cnt_p, NP, rowptr_p);

  // fused scatter (ps/sp only, latency-bound) + input projections
  scatter_proj_kernel<<<NB_SC + NB_PP + NB_PS, 256, 0, stream>>>(
      ps_src, ps_dst, sp_src, sp_dst,
      cnt_s, cnt_p, sorted_ps, sorted_sp,
      x_pol, Wp, bp, P0, x_stock, Wst, bst, S0);

  int aggGrid = (NS + NP + 3) / 4;
  int tS = ((NS + 255) / 256) * 2;   // N=512 -> 2 column tiles per M tile
  int tP = ((NP + 255) / 256) * 2;

  // conv1: MS = mean_ps(P0), MP = mean_sp(S0); then paired GEMM (flattened grid)
  agg2_kernel<<<aggGrid, 256, 0, stream>>>(P0, rowptr_s, sorted_ps, MS, NS,
                                           S0, rowptr_p, sorted_sp, MP, NP);
  {
    GemmProb a = {MS, Wt[0], S0, Wt[1], c1_ps_bl, S1, NS, 1};
    GemmProb b = {MP, Wt[2], P0, Wt[3], c1_sp_bl, P1, NP, 1};
    gemm_mfma256<<<tS + tP, 512, 0, stream>>>(a, b, tS);
  }

  // conv2
  agg2_kernel<<<aggGrid, 256, 0, stream>>>(P1, rowptr_s, sorted_ps, MS, NS,
                                           S1, rowptr_p, sorted_sp, MP, NP);
  {
    GemmProb a = {MS, Wt[4], S1, Wt[5], c2_ps_bl, S0, NS, 1};
    GemmProb b = {MP, Wt[6], P1, Wt[7], c2_sp_bl, P0, NP, 1};
    gemm_mfma256<<<tS + tP, 512, 0, stream>>>(a, b, tS);
  }

  // decoder precompute pair: Adec = hp2 @ d1W[0:512,:] + d1b (bias folded), Bdec = hs2 @ d1W[512:1024,:]
  {
    GemmProb a = {P0, Wt[8], nullptr, nullptr, d1b, MP, NP, 0};
    GemmProb b = {S0, Wt[9], nullptr, nullptr, nullptr, MS, NS, 0};
    gemm_mfma256<<<tP + tS, 512, 0, stream>>>(a, b, tP);
  }

  // edge decoder (bf16 MFMA, CSR-free): grid-stride, 2048 blocks (8/CU, full occupancy)
  edge_mfma_kernel<<<2048, 256, 0, stream>>>(MP, MS, w2f, d1W, d2b,
                                             trow, tcol, attr, out);
}